// Round 3
// baseline (568.249 us; speedup 1.0000x reference)
//
#include <hip/hip_runtime.h>
#include <math.h>

// Problem constants (match reference setup_inputs)
#define N_NODES   50000
#define E0_EDGES  800000
#define E_TOT     (E0_EDGES + N_NODES)   // self-loops appended
#define FIN       128
#define F1        256                    // HEADS*OUT_CH layer1
#define H1        4
#define C1        64
#define C2        64
#define NEG_SLOPE 0.2f

// ---------------------------------------------------------------------------
// Tiled fp32 GEMM: C[M,N] = A[M,K] @ B[K,N].  BM=BN=64, BK=32, 256 threads,
// 4x4 micro-tile per thread. K,N multiples of 32/64 in this problem; M guarded.
// ---------------------------------------------------------------------------
__global__ __launch_bounds__(256) void gemm_f32(
    const float* __restrict__ A, const float* __restrict__ B,
    float* __restrict__ C, int M, int N, int K) {
  __shared__ float As[64][33];   // +1 pad: conflict-free As[m][k] reads
  __shared__ float Bs[32][64];
  const int tid = threadIdx.x;
  const int tx = tid & 15, ty = tid >> 4;
  const int row0 = blockIdx.x * 64;
  const int col0 = blockIdx.y * 64;
  float acc[4][4] = {};
  for (int k0 = 0; k0 < K; k0 += 32) {
    // A tile: 64x32 floats = 512 float4 slots, 2 per thread
#pragma unroll
    for (int i = 0; i < 2; ++i) {
      int idx = tid + i * 256;
      int r = idx >> 3;            // 8 float4 per 32-wide row
      int c4 = (idx & 7) * 4;
      int gr = row0 + r;
      float4 v;
      if (gr < M) v = *reinterpret_cast<const float4*>(&A[(size_t)gr * K + k0 + c4]);
      else        v = make_float4(0.f, 0.f, 0.f, 0.f);
      As[r][c4] = v.x; As[r][c4 + 1] = v.y; As[r][c4 + 2] = v.z; As[r][c4 + 3] = v.w;
    }
    // B tile: 32x64 floats
#pragma unroll
    for (int i = 0; i < 2; ++i) {
      int idx = tid + i * 256;
      int r = idx >> 4;            // 16 float4 per 64-wide row
      int c4 = (idx & 15) * 4;
      float4 v = *reinterpret_cast<const float4*>(&B[(size_t)(k0 + r) * N + col0 + c4]);
      *reinterpret_cast<float4*>(&Bs[r][c4]) = v;
    }
    __syncthreads();
#pragma unroll
    for (int k = 0; k < 32; ++k) {
      float a[4], b[4];
#pragma unroll
      for (int i = 0; i < 4; ++i) a[i] = As[ty * 4 + i][k];
#pragma unroll
      for (int j = 0; j < 4; ++j) b[j] = Bs[k][tx * 4 + j];
#pragma unroll
      for (int i = 0; i < 4; ++i)
#pragma unroll
        for (int j = 0; j < 4; ++j) acc[i][j] = fmaf(a[i], b[j], acc[i][j]);
    }
    __syncthreads();
  }
#pragma unroll
  for (int i = 0; i < 4; ++i) {
    int gr = row0 + ty * 4 + i;
    if (gr < M) {
      float4 v = {acc[i][0], acc[i][1], acc[i][2], acc[i][3]};
      *reinterpret_cast<float4*>(&C[(size_t)gr * N + col0 + tx * 4]) = v;
    }
  }
}

// ---------------------------------------------------------------------------
// CSR-by-dst build.  edge_index is int32 (harness passes integer arrays as int).
// Layout: ei[0..E0) = src row, ei[E0..2*E0) = dst row. Self-loops appended.
// ---------------------------------------------------------------------------
__global__ __launch_bounds__(256) void deg_kernel(
    const int* __restrict__ ei, int* __restrict__ count) {
  int e = blockIdx.x * 256 + threadIdx.x;
  if (e >= E_TOT) return;
  int dst = (e < E0_EDGES) ? ei[E0_EDGES + e] : (e - E0_EDGES);
  atomicAdd(&count[dst], 1);
}

__global__ __launch_bounds__(1024) void scan_kernel(
    const int* __restrict__ count, int* __restrict__ offset, int n) {
  __shared__ int wsum[16];
  const int tid = threadIdx.x;
  const int lane = tid & 63, wid = tid >> 6;
  int running = 0;
  for (int base = 0; base < n; base += 1024) {
    int i = base + tid;
    int v = (i < n) ? count[i] : 0;
    int sv = v;
#pragma unroll
    for (int d = 1; d < 64; d <<= 1) {
      int t = __shfl_up(sv, d);
      if (lane >= d) sv += t;
    }
    if (lane == 63) wsum[wid] = sv;
    __syncthreads();
    if (tid < 16) {
      int ws = wsum[tid];
#pragma unroll
      for (int d = 1; d < 16; d <<= 1) {
        int t = __shfl_up(ws, d, 16);
        if (tid >= d) ws += t;
      }
      wsum[tid] = ws;
    }
    __syncthreads();
    int wadd = (wid > 0) ? wsum[wid - 1] : 0;
    int total = wsum[15];
    if (i < n) offset[i] = running + wadd + sv - v;   // exclusive
    running += total;
    __syncthreads();
  }
  if (tid == 0) offset[n] = running;
}

__global__ __launch_bounds__(256) void scatter_kernel(
    const int* __restrict__ ei, const int* __restrict__ offset,
    int* __restrict__ cursor, int* __restrict__ csr_src) {
  int e = blockIdx.x * 256 + threadIdx.x;
  if (e >= E_TOT) return;
  int src, dst;
  if (e < E0_EDGES) { src = ei[e]; dst = ei[E0_EDGES + e]; }
  else              { src = e - E0_EDGES; dst = src; }
  int pos = offset[dst] + atomicAdd(&cursor[dst], 1);
  csr_src[pos] = src;
}

// ---------------------------------------------------------------------------
// alpha_s/alpha_d: layer 1 (H=4,C=64): block=256 handles one node, wave=head
// ---------------------------------------------------------------------------
__global__ __launch_bounds__(256) void alphas1_kernel(
    const float* __restrict__ h1, const float* __restrict__ a_s,
    const float* __restrict__ a_d, float* __restrict__ as,
    float* __restrict__ ad, int n) {
  int node = blockIdx.x;
  int t = threadIdx.x, lane = t & 63, hd = t >> 6;
  float hv = h1[(size_t)node * F1 + t];
  float vs = hv * a_s[t];
  float vd = hv * a_d[t];
#pragma unroll
  for (int d = 1; d < 64; d <<= 1) {
    vs += __shfl_xor(vs, d);
    vd += __shfl_xor(vd, d);
  }
  if (lane == 0) { as[node * H1 + hd] = vs; ad[node * H1 + hd] = vd; }
}

// layer 2 (H=1,C=64): wave per node, 4 nodes per block
__global__ __launch_bounds__(256) void alphas2_kernel(
    const float* __restrict__ h2, const float* __restrict__ a_s,
    const float* __restrict__ a_d, float* __restrict__ as,
    float* __restrict__ ad, int n) {
  int lane = threadIdx.x & 63;
  int node = blockIdx.x * 4 + (threadIdx.x >> 6);
  if (node >= n) return;
  float hv = h2[(size_t)node * C2 + lane];
  float vs = hv * a_s[lane];
  float vd = hv * a_d[lane];
#pragma unroll
  for (int d = 1; d < 64; d <<= 1) {
    vs += __shfl_xor(vs, d);
    vd += __shfl_xor(vd, d);
  }
  if (lane == 0) { as[node] = vs; ad[node] = vd; }
}

// ---------------------------------------------------------------------------
// Aggregation layer 1: wave per dst node. Lane l owns channels 4l..4l+3
// (head = l>>4). 3 passes: max, denom, weighted gather of h1[src] rows.
// Epilogue: +b1, ReLU -> out1.
// ---------------------------------------------------------------------------
__global__ __launch_bounds__(256) void aggregate1_kernel(
    const float* __restrict__ h1, const float* __restrict__ as,
    const float* __restrict__ ad, const int* __restrict__ csr_src,
    const int* __restrict__ offset, const float* __restrict__ b1,
    float* __restrict__ out1, int n) {
  const int lane = threadIdx.x & 63;
  const int node = blockIdx.x * 4 + (threadIdx.x >> 6);
  if (node >= n) return;
  const int beg = offset[node], end = offset[node + 1];
  const int hl = lane >> 4;
  const float4 advv = *reinterpret_cast<const float4*>(&ad[node * H1]);
  const float adv[4] = {advv.x, advv.y, advv.z, advv.w};

  float m[4] = {-3.4e38f, -3.4e38f, -3.4e38f, -3.4e38f};
  for (int e = beg + lane; e < end; e += 64) {
    int s = csr_src[e];
    const float4 sv = *reinterpret_cast<const float4*>(&as[s * H1]);
    const float svv[4] = {sv.x, sv.y, sv.z, sv.w};
#pragma unroll
    for (int h = 0; h < 4; ++h) {
      float ev = svv[h] + adv[h];
      ev = ev >= 0.f ? ev : NEG_SLOPE * ev;
      m[h] = fmaxf(m[h], ev);
    }
  }
#pragma unroll
  for (int h = 0; h < 4; ++h)
#pragma unroll
    for (int d = 1; d < 64; d <<= 1) m[h] = fmaxf(m[h], __shfl_xor(m[h], d));

  float den[4] = {0.f, 0.f, 0.f, 0.f};
  for (int e = beg + lane; e < end; e += 64) {
    int s = csr_src[e];
    const float4 sv = *reinterpret_cast<const float4*>(&as[s * H1]);
    const float svv[4] = {sv.x, sv.y, sv.z, sv.w};
#pragma unroll
    for (int h = 0; h < 4; ++h) {
      float ev = svv[h] + adv[h];
      ev = ev >= 0.f ? ev : NEG_SLOPE * ev;
      den[h] += __expf(ev - m[h]);
    }
  }
#pragma unroll
  for (int h = 0; h < 4; ++h) {
#pragma unroll
    for (int d = 1; d < 64; d <<= 1) den[h] += __shfl_xor(den[h], d);
    den[h] = 1.f / (den[h] + 1e-16f);
  }

  float4 acc = make_float4(0.f, 0.f, 0.f, 0.f);
  const float mh = m[hl], dh = den[hl], adh = adv[hl];
  for (int e = beg; e < end; ++e) {
    int s = csr_src[e];                              // uniform across wave
    float ev = as[s * H1 + hl] + adh;
    ev = ev >= 0.f ? ev : NEG_SLOPE * ev;
    float w = __expf(ev - mh) * dh;
    const float4 hv = *reinterpret_cast<const float4*>(&h1[(size_t)s * F1 + lane * 4]);
    acc.x = fmaf(w, hv.x, acc.x);
    acc.y = fmaf(w, hv.y, acc.y);
    acc.z = fmaf(w, hv.z, acc.z);
    acc.w = fmaf(w, hv.w, acc.w);
  }
  const float4 bb = *reinterpret_cast<const float4*>(&b1[lane * 4]);
  float4 o;
  o.x = fmaxf(acc.x + bb.x, 0.f);
  o.y = fmaxf(acc.y + bb.y, 0.f);
  o.z = fmaxf(acc.z + bb.z, 0.f);
  o.w = fmaxf(acc.w + bb.w, 0.f);
  *reinterpret_cast<float4*>(&out1[(size_t)node * F1 + lane * 4]) = o;
}

// Aggregation layer 2: wave per dst node, lane owns channel `lane`. +b2, no ReLU.
__global__ __launch_bounds__(256) void aggregate2_kernel(
    const float* __restrict__ h2, const float* __restrict__ as,
    const float* __restrict__ ad, const int* __restrict__ csr_src,
    const int* __restrict__ offset, const float* __restrict__ b2,
    float* __restrict__ out, int n) {
  const int lane = threadIdx.x & 63;
  const int node = blockIdx.x * 4 + (threadIdx.x >> 6);
  if (node >= n) return;
  const int beg = offset[node], end = offset[node + 1];
  const float adv = ad[node];

  float m = -3.4e38f;
  for (int e = beg + lane; e < end; e += 64) {
    float ev = as[csr_src[e]] + adv;
    ev = ev >= 0.f ? ev : NEG_SLOPE * ev;
    m = fmaxf(m, ev);
  }
#pragma unroll
  for (int d = 1; d < 64; d <<= 1) m = fmaxf(m, __shfl_xor(m, d));

  float den = 0.f;
  for (int e = beg + lane; e < end; e += 64) {
    float ev = as[csr_src[e]] + adv;
    ev = ev >= 0.f ? ev : NEG_SLOPE * ev;
    den += __expf(ev - m);
  }
#pragma unroll
  for (int d = 1; d < 64; d <<= 1) den += __shfl_xor(den, d);
  const float inv = 1.f / (den + 1e-16f);

  float acc = 0.f;
  for (int e = beg; e < end; ++e) {
    int s = csr_src[e];
    float ev = as[s] + adv;
    ev = ev >= 0.f ? ev : NEG_SLOPE * ev;
    float w = __expf(ev - m) * inv;
    acc = fmaf(w, h2[(size_t)s * C2 + lane], acc);
  }
  out[(size_t)node * C2 + lane] = acc + b2[lane];
}

// ---------------------------------------------------------------------------
extern "C" void kernel_launch(void* const* d_in, const int* in_sizes, int n_in,
                              void* d_out, int out_size, void* d_ws, size_t ws_size,
                              hipStream_t stream) {
  const float* x      = (const float*)d_in[0];
  const int*   ei     = (const int*)d_in[1];      // int32! (JAX x64 disabled)
  const float* W1     = (const float*)d_in[2];
  const float* a_src1 = (const float*)d_in[3];
  const float* a_dst1 = (const float*)d_in[4];
  const float* b1     = (const float*)d_in[5];
  const float* W2     = (const float*)d_in[6];
  const float* a_src2 = (const float*)d_in[7];
  const float* a_dst2 = (const float*)d_in[8];
  const float* b2     = (const float*)d_in[9];
  float*       out    = (float*)d_out;

  const int n = N_NODES;

  // Workspace carve (256B-aligned chunks). h2 aliases h1 (dead after aggregate1).
  // Total ~103.4 MiB.
  char* w = (char*)d_ws;
  float* h1   = (float*)w;  w += (size_t)n * F1 * 4;        // 51.2 MB
  float* out1 = (float*)w;  w += (size_t)n * F1 * 4;        // 51.2 MB
  float* as1  = (float*)w;  w += (size_t)n * H1 * 4;        // 800 KB
  float* ad1  = (float*)w;  w += (size_t)n * H1 * 4;
  float* as2  = (float*)w;  w += 200192;
  float* ad2  = (float*)w;  w += 200192;
  int*   cnt  = (int*)w;    w += 200192;
  int*   off  = (int*)w;    w += 200192;
  int*   cur  = (int*)w;    w += 200192;
  int*   csr  = (int*)w;    w += 3400192;
  float* h2   = h1;                                          // alias

  // --- CSR build (shared by both layers) ---
  hipMemsetAsync(cnt, 0, (size_t)n * 4, stream);
  hipMemsetAsync(cur, 0, (size_t)n * 4, stream);
  deg_kernel<<<(E_TOT + 255) / 256, 256, 0, stream>>>(ei, cnt);
  scan_kernel<<<1, 1024, 0, stream>>>(cnt, off, n);
  scatter_kernel<<<(E_TOT + 255) / 256, 256, 0, stream>>>(ei, off, cur, csr);

  // --- Layer 1 ---
  {
    dim3 grid((n + 63) / 64, F1 / 64);
    gemm_f32<<<grid, 256, 0, stream>>>(x, W1, h1, n, F1, FIN);
  }
  alphas1_kernel<<<n, 256, 0, stream>>>(h1, a_src1, a_dst1, as1, ad1, n);
  aggregate1_kernel<<<(n + 3) / 4, 256, 0, stream>>>(h1, as1, ad1, csr, off, b1, out1, n);

  // --- Layer 2 ---
  {
    dim3 grid((n + 63) / 64, C2 / 64);
    gemm_f32<<<grid, 256, 0, stream>>>(out1, W2, h2, n, C2, F1);
  }
  alphas2_kernel<<<(n + 3) / 4, 256, 0, stream>>>(h2, a_src2, a_dst2, as2, ad2, n);
  aggregate2_kernel<<<(n + 3) / 4, 256, 0, stream>>>(h2, as2, ad2, csr, off, b2, out, n);
}